// Round 10
// baseline (1023.450 us; speedup 1.0000x reference)
//
#include <hip/hip_runtime.h>

#define QN 8
#define KN 1024
#define DN 256
#define NROWS 32768
#define IDX_BASE 8388608
#define LOSS_OFF 8650752
#define MARGIN 5e-3f
#define LCAP 4096u

// ws layout (float offsets)
#define WS_LOSS 0
#define WS_CNORM 8
#define WS_CSPLIT 12623880   // bf16[2097152], fragment-major layout (see prep_cast)

// dynamic LDS layout (bytes). 32-row tile -> 50 KB -> 3 blocks/CU
// = 12 waves/CU = 3 waves/SIMD at the 170-reg/wave budget (512-reg file /
// 3 waves). Register demand ~150 fits WITHOUT spilling (R7/R9's 4-wave
// 128-reg budget forced ~100 MB of scratch traffic; R8's unconstrained
// allocation ran ~152 total and dropped to 1 block/CU).
#define SM_RES   0           // 33280: float[32][260] residual (256 data + 4 pad)
#define SM_LCAND 33280       // 16384: uint[4096] id-only candidates
#define SM_CHC   49664       // 256
#define SM_ANS   49920       // 128
#define SM_RMIN  50048       // 128
#define SM_LCNT  50176       // 16 (lcnt @ +0, lsum @ +4)
#define SM_BYTES 50192
#define RESW 260

typedef __attribute__((ext_vector_type(8))) short short8v;
typedef __attribute__((ext_vector_type(4))) float f32x4;

static __device__ __forceinline__ unsigned short f2bf(float x) {
  unsigned int u = __float_as_uint(x);
  unsigned int r = (u + 0x7fffu + ((u >> 16) & 1u)) >> 16;
  return (unsigned short)r;
}

// HW RNE f32->bf16 pair; bit-identical to f2bf for finite inputs.
static __device__ __forceinline__ unsigned cvt_pk_bf16(float lo, float hi) {
  unsigned r;
  asm("v_cvt_pk_bf16_f32 %0, %1, %2" : "=v"(r) : "v"(lo), "v"(hi));
  return r;
}

// numpy pairwise sum-of-squares over 256 floats (validated: absmax 0.0)
__device__ __forceinline__ float sum256_sq_np(const float* p) {
  float h[2];
#pragma unroll
  for (int half = 0; half < 2; ++half) {
    const float* a = p + half * 128;
    float r[8];
#pragma unroll
    for (int j = 0; j < 8; ++j) r[j] = __fmul_rn(a[j], a[j]);
    for (int i = 8; i < 128; i += 8) {
#pragma unroll
      for (int j = 0; j < 8; ++j) r[j] = __fadd_rn(r[j], __fmul_rn(a[i + j], a[i + j]));
    }
    h[half] = __fadd_rn(__fadd_rn(__fadd_rn(r[0], r[1]), __fadd_rn(r[2], r[3])),
                        __fadd_rn(__fadd_rn(r[4], r[5]), __fadd_rn(r[6], r[7])));
  }
  return __fadd_rn(h[0], h[1]);
}

__global__ void rvq_prep_norm(const float* __restrict__ cb, float* __restrict__ ws) {
  int g = blockIdx.x * blockDim.x + threadIdx.x;
  if (g < 8) ws[WS_LOSS + g] = 0.f;
  if (g < QN * KN) ws[WS_CNORM + g] = sum256_sq_np(cb + (size_t)g * DN);
}

// Fragment-major bf16 codebook: 16B chunk index (per q) =
//   c*4096 + wc*1024 + kk*256 + s*128 + j*64 + lane
// holding code (wc*32 + j*16 + (lane&15)), dims [kk*64 + s*32 + (lane>>4)*8, +8).
__global__ void rvq_prep_cast(const float* __restrict__ cb, unsigned short* __restrict__ cs) {
  int gid = blockIdx.x * blockDim.x + threadIdx.x;
  uint4* s4 = (uint4*)cs;
#pragma unroll
  for (int k = 0; k < 2; ++k) {
    int ci = gid + k * 131072;               // 262144 chunks total
    int q = ci >> 15, rem = ci & 32767;
    int lane = rem & 63, fid = rem >> 6;
    int j = fid & 1, s = (fid >> 1) & 1, kk = (fid >> 2) & 3, wc = (fid >> 4) & 3, c = fid >> 6;
    int code = wc * 32 + j * 16 + (lane & 15);
    int doff = kk * 64 + s * 32 + (lane >> 4) * 8;
    const float4* src = (const float4*)(cb + ((size_t)(q * 1024 + c * 128 + code) * 256 + doff));
    float4 v0 = src[0], v1 = src[1];
    uint4 w;
    w.x = (unsigned)f2bf(v0.x) | ((unsigned)f2bf(v0.y) << 16);
    w.y = (unsigned)f2bf(v0.z) | ((unsigned)f2bf(v0.w) << 16);
    w.z = (unsigned)f2bf(v1.x) | ((unsigned)f2bf(v1.y) << 16);
    w.w = (unsigned)f2bf(v1.z) | ((unsigned)f2bf(v1.w) << 16);
    s4[ci] = w;
  }
}

// Single fused kernel, all 8 quantizers. 32-row tile, 256 threads = 4 waves
// (wc = wv, each wave: 32 rows x 32 codes per chunk, areg[2][2][4], acc[2][2]
// -- per-wave work shape identical to R9). 50 KB LDS -> 3 independent
// blocks/CU -> 3 waves/SIMD at the no-spill 170-reg budget. Barrier-free
// screen (racy-safe superset threshold; exact recheck resolves identically).
// Screen d expression, MFMA (kk,s) order per acc, margin, serial-fmaf
// recheck, u64 tie-break, np-exact update: bit-identical to validated R9.
__global__ __launch_bounds__(256)
__attribute__((amdgpu_waves_per_eu(3, 3)))
void rvq_fused_all(const float* __restrict__ z,
                   const float* __restrict__ cb,
                   float* __restrict__ ws,
                   float* __restrict__ out) {
  extern __shared__ __align__(16) char smem[];
  float* RES = (float*)(smem + SM_RES);                // [32][260]
  unsigned int* lcand = (unsigned int*)(smem + SM_LCAND);
  unsigned long long* chc = (unsigned long long*)(smem + SM_CHC);
  float* an_s = (float*)(smem + SM_ANS);
  unsigned int* rowmin = (unsigned int*)(smem + SM_RMIN);
  unsigned int* lcnt = (unsigned int*)(smem + SM_LCNT);
  float* lsum = (float*)(smem + SM_LCNT + 4);

  const int tid = threadIdx.x;
  const int row0 = blockIdx.x * 32;
  const int wv = tid >> 6, lane = tid & 63, quad = lane >> 4, l15 = lane & 15;
  const int wc = wv;                         // 4 waves = 4 code quarters; all rows

  // ---- init: copy z tile -> LDS RES (f32 exact), then ANORM(z) np-exact ----
  const float4* zb = (const float4*)(z + (size_t)row0 * DN);
#pragma unroll
  for (int k = 0; k < 8; ++k) {
    int fi = k * 256 + tid;                  // float4 index in 32x256 tile
    int rr = fi >> 6, dd = (fi & 63) * 4;
    *(float4*)&RES[rr * RESW + dd] = zb[fi];
  }
  if (tid == 0) *lsum = 0.f;
  __syncthreads();
  if (tid < 32) an_s[tid] = sum256_sq_np(&RES[tid * RESW]);

  const uint4* Bf = (const uint4*)((const unsigned short*)(ws + WS_CSPLIT));

#pragma unroll 1
  for (int q = 0; q < QN; ++q) {
    const bool last = (q == QN - 1);

    __syncthreads();                         // RES/an_s stable; prior-q consumers done
    if (tid < 32) {
      rowmin[tid] = 0x7f7fffffu;
      chc[tid] = ~0ull;
    }
    if (tid == 0) *lcnt = 0u;

    // a-fragments: read f32 from LDS once per q, cvt RNE -> bf16 regs (16 frags)
    short8v areg[2][2][4];                   // [i][s][kk] = 64 VGPR
#pragma unroll
    for (int kk = 0; kk < 4; ++kk) {
#pragma unroll
      for (int s = 0; s < 2; ++s) {
#pragma unroll
        for (int i = 0; i < 2; ++i) {
          int ra = i * 16 + l15;
          int g = kk * 8 + s * 4 + quad;     // 8-dim group: dims g*8..g*8+8
          const float* fp = &RES[ra * RESW + g * 8];
          float4 v0 = *(const float4*)fp;
          float4 v1 = *(const float4*)(fp + 4);
          uint4 w;
          w.x = cvt_pk_bf16(v0.x, v0.y);
          w.y = cvt_pk_bf16(v0.z, v0.w);
          w.z = cvt_pk_bf16(v1.x, v1.y);
          w.w = cvt_pk_bf16(v1.z, v1.w);
          areg[i][s][kk] = *(short8v*)&w;
        }
      }
    }
    __syncthreads();                         // resets visible; screen may start

    // ---- screen: 8 chunks of 128 codes, barrier-free ----
    const uint4* Bl = Bf + ((size_t)q * 32768 + wc * 1024 + lane);
    const float* cnq_g = ws + WS_CNORM + q * KN;
    for (int c = 0; c < 8; ++c) {
      float cnr[2];                          // L1-hot scalar norms
#pragma unroll
      for (int j = 0; j < 2; ++j) cnr[j] = cnq_g[c * 128 + wc * 32 + j * 16 + l15];

      f32x4 acc[2][2];
#pragma unroll
      for (int i = 0; i < 2; ++i)
#pragma unroll
        for (int j = 0; j < 2; ++j) acc[i][j] = (f32x4){0.f, 0.f, 0.f, 0.f};

      const uint4* Bc = Bl + c * 4096;
#pragma unroll
      for (int kk = 0; kk < 4; ++kk) {
#pragma unroll
        for (int s = 0; s < 2; ++s) {        // braw scoped per-s: 8 live VGPR
          uint4 braw[2];
#pragma unroll
          for (int j = 0; j < 2; ++j)
            braw[j] = Bc[kk * 256 + s * 128 + j * 64];
#pragma unroll
          for (int i = 0; i < 2; ++i)
#pragma unroll
            for (int j = 0; j < 2; ++j)
              acc[i][j] = __builtin_amdgcn_mfma_f32_16x16x32_bf16(
                  areg[i][s][kk], *(const short8v*)&braw[j], acc[i][j], 0, 0, 0);
        }
      }

      // merged epilogue: per-row wave-min, racy-safe threshold, append.
      // thr = min(rowmin_read, own chunk wave-min) + MARGIN >= final thr
      // -> candidate superset; exact recheck resolves identically.
#pragma unroll
      for (int i = 0; i < 2; ++i) {
#pragma unroll
        for (int reg = 0; reg < 4; ++reg) {
          int rl = i * 16 + quad * 4 + reg;
          float an = an_s[rl];
          float d0 = __fadd_rn(__fadd_rn(an, -2.0f * acc[i][0][reg]), cnr[0]);
          float d1 = __fadd_rn(__fadd_rn(an, -2.0f * acc[i][1][reg]), cnr[1]);
          float bd = 3.402823466e+38f;
          bd = (d0 < bd) ? d0 : bd;
          bd = (d1 < bd) ? d1 : bd;
#pragma unroll
          for (int m = 1; m <= 8; m <<= 1) {
            float od = __shfl_xor(bd, m, 64);
            bd = (od < bd) ? od : bd;
          }
          float rmf = __uint_as_float(rowmin[rl]);     // racy read: only tightens
          if (l15 == 0) atomicMin(&rowmin[rl], __float_as_uint(bd));
          float tb = (bd < rmf) ? bd : rmf;
          float thr = tb + MARGIN;
          if (d0 <= thr) {
            unsigned int p = atomicAdd(lcnt, 1u);
            if (p < LCAP)
              lcand[p] = ((unsigned)rl << 10) | (unsigned)(c * 128 + wc * 32 + l15);
          }
          if (d1 <= thr) {
            unsigned int p = atomicAdd(lcnt, 1u);
            if (p < LCAP)
              lcand[p] = ((unsigned)rl << 10) | (unsigned)(c * 128 + wc * 32 + 16 + l15);
          }
        }
      }
    }
    __syncthreads();                         // appends + final rowmin + lcnt visible

    // ---- exact recheck: residual rows from LDS, codebook f32 from global ----
    const float* cbq = cb + (size_t)q * KN * DN;
    const float* cnq = ws + WS_CNORM + q * KN;
    unsigned int n = *lcnt;
    if (n <= LCAP) {
      for (unsigned int e = tid; e < n; e += 256u) {
        unsigned int en = lcand[e];
        int rl = en >> 10, code = en & 1023;
        const float* r = &RES[rl * RESW];
        const float* cc = cbq + (size_t)code * DN;
        float B = 0.f;
#pragma unroll 16
        for (int d = 0; d < DN; ++d) B = fmaf(r[d], cc[d], B);   // exact serial chain
        float de = __fadd_rn(__fadd_rn(an_s[rl], -2.0f * B), cnq[code]);
        unsigned long long key = ((unsigned long long)__float_as_uint(de) << 32) | (unsigned)code;
        atomicMin(&chc[rl], key);
      }
    } else {
      // safety fallback: exhaustive exact argmin (correct; expected never)
      for (int e = tid; e < 32 * 1024; e += 256) {
        int rl = e >> 10, code = e & 1023;
        const float* r = &RES[rl * RESW];
        const float* cc = cbq + (size_t)code * DN;
        float B = 0.f;
#pragma unroll 16
        for (int d = 0; d < DN; ++d) B = fmaf(r[d], cc[d], B);
        float de = __fadd_rn(__fadd_rn(an_s[rl], -2.0f * B), cnq[code]);
        unsigned long long key = ((unsigned long long)__float_as_uint(de) << 32) | (unsigned)code;
        atomicMin(&chc[rl], key);
      }
    }
    __syncthreads();                        // chc final

    // ---- np-exact update in LDS: 2 passes x 16 rows, 16 thr/row x 16 dims ----
    const int ur = tid >> 4, ud = tid & 15;  // ur in 0..15
    float lp = 0.f;
    for (int pass = 0; pass < 2; ++pass) {
      int rl = pass * 16 + ur;
      int row = row0 + rl;
      int idx = (int)(chc[rl] & 1023u);
      if (ud == 0) out[IDX_BASE + (size_t)q * NROWS + row] = (float)idx;

      float4* r4 = (float4*)&RES[rl * RESW + ud * 16];
      const float4* q4 = (const float4*)(cb + ((size_t)q * KN + idx) * DN) + ud * 4;
      float4 rnb[4];
#pragma unroll
      for (int t = 0; t < 4; ++t) {
        float4 r = r4[t], qv = q4[t];
        float tx = __fadd_rn(qv.x, -r.x), ty = __fadd_rn(qv.y, -r.y);
        float tz = __fadd_rn(qv.z, -r.z), tw = __fadd_rn(qv.w, -r.w);
        float sx = __fadd_rn(r.x, tx), sy = __fadd_rn(r.y, ty);
        float sz = __fadd_rn(r.z, tz), sw = __fadd_rn(r.w, tw);
        rnb[t] = make_float4(__fadd_rn(r.x, -sx), __fadd_rn(r.y, -sy),
                             __fadd_rn(r.z, -sz), __fadd_rn(r.w, -sw));
        lp = fmaf(tx, tx, lp); lp = fmaf(ty, ty, lp);
        lp = fmaf(tz, tz, lp); lp = fmaf(tw, tw, lp);
      }

      if (last) {
        const float4* z4 = (const float4*)(z + (size_t)row * DN) + ud * 4;
        float4* o4 = (float4*)(out + (size_t)row * DN) + ud * 4;
#pragma unroll
        for (int t = 0; t < 4; ++t) {
          float4 zv = z4[t];
          o4[t] = make_float4(__fadd_rn(zv.x, -rnb[t].x), __fadd_rn(zv.y, -rnb[t].y),
                              __fadd_rn(zv.z, -rnb[t].z), __fadd_rn(zv.w, -rnb[t].w));
        }
      } else {
#pragma unroll
        for (int t = 0; t < 4; ++t) r4[t] = rnb[t];   // residual stays in LDS
      }
    }

#pragma unroll
    for (int off = 32; off > 0; off >>= 1) lp += __shfl_down(lp, off, 64);
    if (lane == 0) atomicAdd(lsum, lp);     // LDS f32 add: 4 wave partials

    __syncthreads();                        // RES updates + lsum complete
    if (!last && tid < 32) an_s[tid] = sum256_sq_np(&RES[tid * RESW]);
    if (tid == 0) {                         // one global atomic per block per q
      atomicAdd(ws + WS_LOSS + q, *lsum);
      *lsum = 0.f;
    }
  }
}

__global__ void rvq_fin(const float* __restrict__ ws, float* __restrict__ out) {
  if (blockIdx.x == 0 && threadIdx.x == 0) {
    float vq = 0.f;
    for (int q = 0; q < QN; ++q) {
      float m = ws[WS_LOSS + q] / 8388608.0f;
      float l = __fadd_rn(m, 0.25f * m);
      vq = __fadd_rn(vq, l);
    }
    out[LOSS_OFF] = vq;
  }
}

extern "C" void kernel_launch(void* const* d_in, const int* in_sizes, int n_in,
                              void* d_out, int out_size, void* d_ws, size_t ws_size,
                              hipStream_t stream) {
  const float* z = (const float*)d_in[0];
  const float* cb = (const float*)d_in[1];
  float* out = (float*)d_out;
  float* ws = (float*)d_ws;

  hipLaunchKernelGGL(rvq_prep_norm, dim3(32), dim3(256), 0, stream, cb, ws);
  hipLaunchKernelGGL(rvq_prep_cast, dim3(512), dim3(256), 0, stream, cb,
                     (unsigned short*)(ws + WS_CSPLIT));
  hipLaunchKernelGGL(rvq_fused_all, dim3(1024), dim3(256), SM_BYTES, stream, z, cb, ws, out);
  hipLaunchKernelGGL(rvq_fin, dim3(1), dim3(64), 0, stream, ws, out);
}

// Round 12
// 709.661 us; speedup vs baseline: 1.4422x; 1.4422x over previous
//
#include <hip/hip_runtime.h>

#define QN 8
#define KN 1024
#define DN 256
#define NROWS 32768
#define IDX_BASE 8388608
#define LOSS_OFF 8650752
#define MARGIN 5e-3f
#define LCAP 3072u

// ws layout (float offsets)
#define WS_LOSS 0
#define WS_CNORM 8
#define WS_CSPLIT 12623880   // bf16[2097152], fragment-major layout (see prep_cast)

// dynamic LDS layout (bytes). 78 KB -> 2 blocks/CU; 512 threads/block ->
// 16 waves/CU = 4 waves/SIMD. (R9 geometry: best measured config.)
#define SM_RES   0           // 66560: float[64][260] residual (256 data + 4 pad)
#define SM_LCAND 66560       // 12288: uint[3072] id-only candidates
#define SM_CHC   78848       // 512
#define SM_ANS   79360       // 256
#define SM_RMIN  79616       // 256
#define SM_LCNT  79872       // 16 (lcnt @ +0, lsum @ +4)
#define SM_BYTES 79888
#define RESW 260

typedef __attribute__((ext_vector_type(8))) short short8v;
typedef __attribute__((ext_vector_type(4))) float f32x4;

static __device__ __forceinline__ unsigned short f2bf(float x) {
  unsigned int u = __float_as_uint(x);
  unsigned int r = (u + 0x7fffu + ((u >> 16) & 1u)) >> 16;
  return (unsigned short)r;
}

// HW RNE f32->bf16 pair; bit-identical to f2bf for finite inputs.
static __device__ __forceinline__ unsigned cvt_pk_bf16(float lo, float hi) {
  unsigned r;
  asm("v_cvt_pk_bf16_f32 %0, %1, %2" : "=v"(r) : "v"(lo), "v"(hi));
  return r;
}

// Exact min over each 16-lane DPP row (== l15 group) via rotation tree:
// after ror 1,2,4,8 every lane holds min over its row's 16 values.
// Bit-identical to the validated shfl_xor(1,2,4,8) butterfly (same value set,
// min is order-independent for the positive normals seen here), but pure
// VALU -- replaces 4 ds_swizzle LDS ops per reduce (R10 diagnosis: LDS unit
// is the per-CU serialized resource).
static __device__ __forceinline__ float min16_dpp(float x) {
  int xi, oi; float of;
  xi = __float_as_int(x);
  oi = __builtin_amdgcn_update_dpp(xi, xi, 0x121, 0xf, 0xf, true);  // row_ror:1
  of = __int_as_float(oi); x = (of < x) ? of : x;
  xi = __float_as_int(x);
  oi = __builtin_amdgcn_update_dpp(xi, xi, 0x122, 0xf, 0xf, true);  // row_ror:2
  of = __int_as_float(oi); x = (of < x) ? of : x;
  xi = __float_as_int(x);
  oi = __builtin_amdgcn_update_dpp(xi, xi, 0x124, 0xf, 0xf, true);  // row_ror:4
  of = __int_as_float(oi); x = (of < x) ? of : x;
  xi = __float_as_int(x);
  oi = __builtin_amdgcn_update_dpp(xi, xi, 0x128, 0xf, 0xf, true);  // row_ror:8
  of = __int_as_float(oi); x = (of < x) ? of : x;
  return x;
}

// numpy pairwise sum-of-squares over 256 floats (validated: absmax 0.0)
__device__ __forceinline__ float sum256_sq_np(const float* p) {
  float h[2];
#pragma unroll
  for (int half = 0; half < 2; ++half) {
    const float* a = p + half * 128;
    float r[8];
#pragma unroll
    for (int j = 0; j < 8; ++j) r[j] = __fmul_rn(a[j], a[j]);
    for (int i = 8; i < 128; i += 8) {
#pragma unroll
      for (int j = 0; j < 8; ++j) r[j] = __fadd_rn(r[j], __fmul_rn(a[i + j], a[i + j]));
    }
    h[half] = __fadd_rn(__fadd_rn(__fadd_rn(r[0], r[1]), __fadd_rn(r[2], r[3])),
                        __fadd_rn(__fadd_rn(r[4], r[5]), __fadd_rn(r[6], r[7])));
  }
  return __fadd_rn(h[0], h[1]);
}

__global__ void rvq_prep_norm(const float* __restrict__ cb, float* __restrict__ ws) {
  int g = blockIdx.x * blockDim.x + threadIdx.x;
  if (g < 8) ws[WS_LOSS + g] = 0.f;
  if (g < QN * KN) ws[WS_CNORM + g] = sum256_sq_np(cb + (size_t)g * DN);
}

// Fragment-major bf16 codebook: 16B chunk index (per q) =
//   c*4096 + wc*1024 + kk*256 + s*128 + j*64 + lane
// holding code (wc*32 + j*16 + (lane&15)), dims [kk*64 + s*32 + (lane>>4)*8, +8).
__global__ void rvq_prep_cast(const float* __restrict__ cb, unsigned short* __restrict__ cs) {
  int gid = blockIdx.x * blockDim.x + threadIdx.x;
  uint4* s4 = (uint4*)cs;
#pragma unroll
  for (int k = 0; k < 2; ++k) {
    int ci = gid + k * 131072;               // 262144 chunks total
    int q = ci >> 15, rem = ci & 32767;
    int lane = rem & 63, fid = rem >> 6;
    int j = fid & 1, s = (fid >> 1) & 1, kk = (fid >> 2) & 3, wc = (fid >> 4) & 3, c = fid >> 6;
    int code = wc * 32 + j * 16 + (lane & 15);
    int doff = kk * 64 + s * 32 + (lane >> 4) * 8;
    const float4* src = (const float4*)(cb + ((size_t)(q * 1024 + c * 128 + code) * 256 + doff));
    float4 v0 = src[0], v1 = src[1];
    uint4 w;
    w.x = (unsigned)f2bf(v0.x) | ((unsigned)f2bf(v0.y) << 16);
    w.y = (unsigned)f2bf(v0.z) | ((unsigned)f2bf(v0.w) << 16);
    w.z = (unsigned)f2bf(v1.x) | ((unsigned)f2bf(v1.y) << 16);
    w.w = (unsigned)f2bf(v1.z) | ((unsigned)f2bf(v1.w) << 16);
    s4[ci] = w;
  }
}

// Single fused kernel, all 8 quantizers. Exact R9 structure (last passing:
// 64-row tile, 512 thr = 8 waves wr2 x wc4, 78 KB LDS, waves_per_eu(4,4),
// single-pass screen with racy-safe superset threshold, one-lane-per-address
// LDS atomics only -- R11's same-address multi-lane atomicMin corrupted
// rowmin and is NOT used). R12 deltas, both value-preserving:
//  - epilogue 16-lane min via DPP row_ror (min16_dpp) instead of 4
//    shfl_xor/ds_swizzle: same exact min, zero LDS ops (256 -> 0 per wave/q).
//  - recheck via float4 loads, same serial fmaf chain order: bit-identical B.
__global__ __launch_bounds__(512)
__attribute__((amdgpu_waves_per_eu(4, 4)))
void rvq_fused_all(const float* __restrict__ z,
                   const float* __restrict__ cb,
                   float* __restrict__ ws,
                   float* __restrict__ out) {
  extern __shared__ __align__(16) char smem[];
  float* RES = (float*)(smem + SM_RES);                // [64][260]
  unsigned int* lcand = (unsigned int*)(smem + SM_LCAND);
  unsigned long long* chc = (unsigned long long*)(smem + SM_CHC);
  float* an_s = (float*)(smem + SM_ANS);
  unsigned int* rowmin = (unsigned int*)(smem + SM_RMIN);
  unsigned int* lcnt = (unsigned int*)(smem + SM_LCNT);
  float* lsum = (float*)(smem + SM_LCNT + 4);

  const int tid = threadIdx.x;
  const int row0 = blockIdx.x * 64;
  const int wv = tid >> 6, lane = tid & 63, quad = lane >> 4, l15 = lane & 15;
  const int wr = wv >> 2, wc = wv & 3;

  // ---- init: copy z tile -> LDS RES (f32 exact), then ANORM(z) np-exact ----
  const float4* zb = (const float4*)(z + (size_t)row0 * DN);
#pragma unroll
  for (int k = 0; k < 8; ++k) {
    int fi = k * 512 + tid;                  // float4 index in 64x256 tile
    int rr = fi >> 6, dd = (fi & 63) * 4;
    *(float4*)&RES[rr * RESW + dd] = zb[fi];
  }
  if (tid == 0) *lsum = 0.f;
  __syncthreads();
  if (tid < 64) an_s[tid] = sum256_sq_np(&RES[tid * RESW]);

  const uint4* Bf = (const uint4*)((const unsigned short*)(ws + WS_CSPLIT));

#pragma unroll 1
  for (int q = 0; q < QN; ++q) {
    const bool last = (q == QN - 1);

    __syncthreads();                         // RES/an_s stable; prior-q consumers done
    if (tid < 64) {
      rowmin[tid] = 0x7f7fffffu;
      chc[tid] = ~0ull;
    }
    if (tid == 0) *lcnt = 0u;

    // a-fragments: read f32 from LDS once per q, cvt RNE -> bf16 regs (16 frags)
    short8v areg[2][2][4];                   // [i][s][kk] = 64 VGPR
#pragma unroll
    for (int kk = 0; kk < 4; ++kk) {
#pragma unroll
      for (int s = 0; s < 2; ++s) {
#pragma unroll
        for (int i = 0; i < 2; ++i) {
          int ra = wr * 32 + i * 16 + l15;
          int g = kk * 8 + s * 4 + quad;     // 8-dim group: dims g*8..g*8+8
          const float* fp = &RES[ra * RESW + g * 8];
          float4 v0 = *(const float4*)fp;
          float4 v1 = *(const float4*)(fp + 4);
          uint4 w;
          w.x = cvt_pk_bf16(v0.x, v0.y);
          w.y = cvt_pk_bf16(v0.z, v0.w);
          w.z = cvt_pk_bf16(v1.x, v1.y);
          w.w = cvt_pk_bf16(v1.z, v1.w);
          areg[i][s][kk] = *(short8v*)&w;
        }
      }
    }
    __syncthreads();                         // resets visible; screen may start

    // ---- screen: 8 chunks of 128 codes, barrier-free ----
    const uint4* Bl = Bf + ((size_t)q * 32768 + wc * 1024 + lane);
    const float* cnq_g = ws + WS_CNORM + q * KN;
    for (int c = 0; c < 8; ++c) {
      float cnr[2];                          // L1-hot scalar norms
#pragma unroll
      for (int j = 0; j < 2; ++j) cnr[j] = cnq_g[c * 128 + wc * 32 + j * 16 + l15];

      f32x4 acc[2][2];
#pragma unroll
      for (int i = 0; i < 2; ++i)
#pragma unroll
        for (int j = 0; j < 2; ++j) acc[i][j] = (f32x4){0.f, 0.f, 0.f, 0.f};

      const uint4* Bc = Bl + c * 4096;
#pragma unroll
      for (int kk = 0; kk < 4; ++kk) {
#pragma unroll
        for (int s = 0; s < 2; ++s) {        // braw scoped per-s: 8 live VGPR
          uint4 braw[2];
#pragma unroll
          for (int j = 0; j < 2; ++j)
            braw[j] = Bc[kk * 256 + s * 128 + j * 64];
#pragma unroll
          for (int i = 0; i < 2; ++i)
#pragma unroll
            for (int j = 0; j < 2; ++j)
              acc[i][j] = __builtin_amdgcn_mfma_f32_16x16x32_bf16(
                  areg[i][s][kk], *(const short8v*)&braw[j], acc[i][j], 0, 0, 0);
        }
      }

      // merged epilogue: per-row wave-min (DPP, no LDS), racy-safe threshold,
      // append. thr = min(rowmin_read, own chunk wave-min) + MARGIN >= final
      // thr -> candidate superset; exact recheck resolves identically.
#pragma unroll
      for (int i = 0; i < 2; ++i) {
#pragma unroll
        for (int reg = 0; reg < 4; ++reg) {
          int rl = wr * 32 + i * 16 + quad * 4 + reg;
          float an = an_s[rl];
          float d0 = __fadd_rn(__fadd_rn(an, -2.0f * acc[i][0][reg]), cnr[0]);
          float d1 = __fadd_rn(__fadd_rn(an, -2.0f * acc[i][1][reg]), cnr[1]);
          float bd = 3.402823466e+38f;
          bd = (d0 < bd) ? d0 : bd;
          bd = (d1 < bd) ? d1 : bd;
          bd = min16_dpp(bd);                // min over 16 l15 lanes, pure VALU
          float rmf = __uint_as_float(rowmin[rl]);     // racy read: only tightens
          if (l15 == 0) atomicMin(&rowmin[rl], __float_as_uint(bd));
          float tb = (bd < rmf) ? bd : rmf;
          float thr = tb + MARGIN;
          if (d0 <= thr) {
            unsigned int p = atomicAdd(lcnt, 1u);
            if (p < LCAP)
              lcand[p] = ((unsigned)rl << 10) | (unsigned)(c * 128 + wc * 32 + l15);
          }
          if (d1 <= thr) {
            unsigned int p = atomicAdd(lcnt, 1u);
            if (p < LCAP)
              lcand[p] = ((unsigned)rl << 10) | (unsigned)(c * 128 + wc * 32 + 16 + l15);
          }
        }
      }
    }
    __syncthreads();                         // appends + final rowmin + lcnt visible

    // ---- exact recheck: residual rows from LDS (float4), codebook f32 global ----
    const float* cbq = cb + (size_t)q * KN * DN;
    const float* cnq = ws + WS_CNORM + q * KN;
    unsigned int n = *lcnt;
    if (n <= LCAP) {
      for (unsigned int e = tid; e < n; e += 512u) {
        unsigned int en = lcand[e];
        int rl = en >> 10, code = en & 1023;
        const float4* rv4 = (const float4*)&RES[rl * RESW];
        const float4* cv4 = (const float4*)(cbq + (size_t)code * DN);
        float B = 0.f;
#pragma unroll 8
        for (int d4 = 0; d4 < 64; ++d4) {    // same serial chain, vector loads
          float4 rv = rv4[d4], cv = cv4[d4];
          B = fmaf(rv.x, cv.x, B); B = fmaf(rv.y, cv.y, B);
          B = fmaf(rv.z, cv.z, B); B = fmaf(rv.w, cv.w, B);
        }
        float de = __fadd_rn(__fadd_rn(an_s[rl], -2.0f * B), cnq[code]);
        unsigned long long key = ((unsigned long long)__float_as_uint(de) << 32) | (unsigned)code;
        atomicMin(&chc[rl], key);
      }
    } else {
      // safety fallback: exhaustive exact argmin (correct; expected never)
      for (int e = tid; e < 64 * 1024; e += 512) {
        int rl = e >> 10, code = e & 1023;
        const float4* rv4 = (const float4*)&RES[rl * RESW];
        const float4* cv4 = (const float4*)(cbq + (size_t)code * DN);
        float B = 0.f;
#pragma unroll 8
        for (int d4 = 0; d4 < 64; ++d4) {
          float4 rv = rv4[d4], cv = cv4[d4];
          B = fmaf(rv.x, cv.x, B); B = fmaf(rv.y, cv.y, B);
          B = fmaf(rv.z, cv.z, B); B = fmaf(rv.w, cv.w, B);
        }
        float de = __fadd_rn(__fadd_rn(an_s[rl], -2.0f * B), cnq[code]);
        unsigned long long key = ((unsigned long long)__float_as_uint(de) << 32) | (unsigned)code;
        atomicMin(&chc[rl], key);
      }
    }
    __syncthreads();                        // chc final

    // ---- np-exact update in LDS: 2 passes x 32 rows, 16 thr/row x 16 dims ----
    const int ur = tid >> 4, ud = tid & 15;  // ur in 0..31
    float lp = 0.f;
    for (int pass = 0; pass < 2; ++pass) {
      int rl = pass * 32 + ur;
      int row = row0 + rl;
      int idx = (int)(chc[rl] & 1023u);
      if (ud == 0) out[IDX_BASE + (size_t)q * NROWS + row] = (float)idx;

      float4* r4 = (float4*)&RES[rl * RESW + ud * 16];
      const float4* q4 = (const float4*)(cb + ((size_t)q * KN + idx) * DN) + ud * 4;
      float4 rnb[4];
#pragma unroll
      for (int t = 0; t < 4; ++t) {
        float4 r = r4[t], qv = q4[t];
        float tx = __fadd_rn(qv.x, -r.x), ty = __fadd_rn(qv.y, -r.y);
        float tz = __fadd_rn(qv.z, -r.z), tw = __fadd_rn(qv.w, -r.w);
        float sx = __fadd_rn(r.x, tx), sy = __fadd_rn(r.y, ty);
        float sz = __fadd_rn(r.z, tz), sw = __fadd_rn(r.w, tw);
        rnb[t] = make_float4(__fadd_rn(r.x, -sx), __fadd_rn(r.y, -sy),
                             __fadd_rn(r.z, -sz), __fadd_rn(r.w, -sw));
        lp = fmaf(tx, tx, lp); lp = fmaf(ty, ty, lp);
        lp = fmaf(tz, tz, lp); lp = fmaf(tw, tw, lp);
      }

      if (last) {
        const float4* z4 = (const float4*)(z + (size_t)row * DN) + ud * 4;
        float4* o4 = (float4*)(out + (size_t)row * DN) + ud * 4;
#pragma unroll
        for (int t = 0; t < 4; ++t) {
          float4 zv = z4[t];
          o4[t] = make_float4(__fadd_rn(zv.x, -rnb[t].x), __fadd_rn(zv.y, -rnb[t].y),
                              __fadd_rn(zv.z, -rnb[t].z), __fadd_rn(zv.w, -rnb[t].w));
        }
      } else {
#pragma unroll
        for (int t = 0; t < 4; ++t) r4[t] = rnb[t];   // residual stays in LDS
      }
    }

#pragma unroll
    for (int off = 32; off > 0; off >>= 1) lp += __shfl_down(lp, off, 64);
    if (lane == 0) atomicAdd(lsum, lp);     // LDS f32 add: 8 wave partials

    __syncthreads();                        // RES updates + lsum complete
    if (!last && tid < 64) an_s[tid] = sum256_sq_np(&RES[tid * RESW]);
    if (tid == 0) {                         // one global atomic per block per q
      atomicAdd(ws + WS_LOSS + q, *lsum);
      *lsum = 0.f;
    }
  }
}

__global__ void rvq_fin(const float* __restrict__ ws, float* __restrict__ out) {
  if (blockIdx.x == 0 && threadIdx.x == 0) {
    float vq = 0.f;
    for (int q = 0; q < QN; ++q) {
      float m = ws[WS_LOSS + q] / 8388608.0f;
      float l = __fadd_rn(m, 0.25f * m);
      vq = __fadd_rn(vq, l);
    }
    out[LOSS_OFF] = vq;
  }
}

extern "C" void kernel_launch(void* const* d_in, const int* in_sizes, int n_in,
                              void* d_out, int out_size, void* d_ws, size_t ws_size,
                              hipStream_t stream) {
  const float* z = (const float*)d_in[0];
  const float* cb = (const float*)d_in[1];
  float* out = (float*)d_out;
  float* ws = (float*)d_ws;

  hipLaunchKernelGGL(rvq_prep_norm, dim3(32), dim3(256), 0, stream, cb, ws);
  hipLaunchKernelGGL(rvq_prep_cast, dim3(512), dim3(256), 0, stream, cb,
                     (unsigned short*)(ws + WS_CSPLIT));
  hipLaunchKernelGGL(rvq_fused_all, dim3(512), dim3(512), SM_BYTES, stream, z, cb, ws, out);
  hipLaunchKernelGGL(rvq_fin, dim3(1), dim3(64), 0, stream, ws, out);
}

// Round 13
// 644.982 us; speedup vs baseline: 1.5868x; 1.1003x over previous
//
#include <hip/hip_runtime.h>

#define QN 8
#define KN 1024
#define DN 256
#define NROWS 32768
#define IDX_BASE 8388608
#define LOSS_OFF 8650752
#define MARGIN 5e-3f
#define LCAP 3072u

// ws layout (float offsets)
#define WS_LOSS 0
#define WS_CNORM 8
#define WS_CSPLIT 12623880   // bf16[2097152], fragment-major layout (see prep_cast)

// dynamic LDS layout (bytes). 78 KB -> 2 blocks/CU; 512 threads/block ->
// 16 waves/CU = 4 waves/SIMD. (R9/R12 geometry.)
#define SM_RES   0           // 66560: float[64][260] residual (256 data + 4 pad)
#define SM_LCAND 66560       // 12288: uint[3072] id-only candidates
#define SM_CHC   78848       // 512
#define SM_ANS   79360       // 256
#define SM_RMIN  79616       // 256
#define SM_LCNT  79872       // 16 (lcnt @ +0, lsum @ +4)
#define SM_BYTES 79888
#define RESW 260

typedef __attribute__((ext_vector_type(8))) short short8v;
typedef __attribute__((ext_vector_type(4))) float f32x4;

static __device__ __forceinline__ unsigned short f2bf(float x) {
  unsigned int u = __float_as_uint(x);
  unsigned int r = (u + 0x7fffu + ((u >> 16) & 1u)) >> 16;
  return (unsigned short)r;
}

// HW RNE f32->bf16 pair; bit-identical to f2bf for finite inputs.
static __device__ __forceinline__ unsigned cvt_pk_bf16(float lo, float hi) {
  unsigned r;
  asm("v_cvt_pk_bf16_f32 %0, %1, %2" : "=v"(r) : "v"(lo), "v"(hi));
  return r;
}

// Exact min over each 16-lane DPP row via rotation tree (validated R12).
static __device__ __forceinline__ float min16_dpp(float x) {
  int xi, oi; float of;
  xi = __float_as_int(x);
  oi = __builtin_amdgcn_update_dpp(xi, xi, 0x121, 0xf, 0xf, true);  // row_ror:1
  of = __int_as_float(oi); x = (of < x) ? of : x;
  xi = __float_as_int(x);
  oi = __builtin_amdgcn_update_dpp(xi, xi, 0x122, 0xf, 0xf, true);  // row_ror:2
  of = __int_as_float(oi); x = (of < x) ? of : x;
  xi = __float_as_int(x);
  oi = __builtin_amdgcn_update_dpp(xi, xi, 0x124, 0xf, 0xf, true);  // row_ror:4
  of = __int_as_float(oi); x = (of < x) ? of : x;
  xi = __float_as_int(x);
  oi = __builtin_amdgcn_update_dpp(xi, xi, 0x128, 0xf, 0xf, true);  // row_ror:8
  of = __int_as_float(oi); x = (of < x) ? of : x;
  return x;
}

// numpy pairwise sum-of-squares over 256 floats (validated: absmax 0.0)
__device__ __forceinline__ float sum256_sq_np(const float* p) {
  float h[2];
#pragma unroll
  for (int half = 0; half < 2; ++half) {
    const float* a = p + half * 128;
    float r[8];
#pragma unroll
    for (int j = 0; j < 8; ++j) r[j] = __fmul_rn(a[j], a[j]);
    for (int i = 8; i < 128; i += 8) {
#pragma unroll
      for (int j = 0; j < 8; ++j) r[j] = __fadd_rn(r[j], __fmul_rn(a[i + j], a[i + j]));
    }
    h[half] = __fadd_rn(__fadd_rn(__fadd_rn(r[0], r[1]), __fadd_rn(r[2], r[3])),
                        __fadd_rn(__fadd_rn(r[4], r[5]), __fadd_rn(r[6], r[7])));
  }
  return __fadd_rn(h[0], h[1]);
}

__global__ void rvq_prep_norm(const float* __restrict__ cb, float* __restrict__ ws) {
  int g = blockIdx.x * blockDim.x + threadIdx.x;
  if (g < 8) ws[WS_LOSS + g] = 0.f;
  if (g < QN * KN) ws[WS_CNORM + g] = sum256_sq_np(cb + (size_t)g * DN);
}

// Fragment-major bf16 codebook: 16B chunk index (per q) =
//   c*4096 + wc*1024 + kk*256 + s*128 + j*64 + lane
// holding code (wc*32 + j*16 + (lane&15)), dims [kk*64 + s*32 + (lane>>4)*8, +8).
__global__ void rvq_prep_cast(const float* __restrict__ cb, unsigned short* __restrict__ cs) {
  int gid = blockIdx.x * blockDim.x + threadIdx.x;
  uint4* s4 = (uint4*)cs;
#pragma unroll
  for (int k = 0; k < 2; ++k) {
    int ci = gid + k * 131072;               // 262144 chunks total
    int q = ci >> 15, rem = ci & 32767;
    int lane = rem & 63, fid = rem >> 6;
    int j = fid & 1, s = (fid >> 1) & 1, kk = (fid >> 2) & 3, wc = (fid >> 4) & 3, c = fid >> 6;
    int code = wc * 32 + j * 16 + (lane & 15);
    int doff = kk * 64 + s * 32 + (lane >> 4) * 8;
    const float4* src = (const float4*)(cb + ((size_t)(q * 1024 + c * 128 + code) * 256 + doff));
    float4 v0 = src[0], v1 = src[1];
    uint4 w;
    w.x = (unsigned)f2bf(v0.x) | ((unsigned)f2bf(v0.y) << 16);
    w.y = (unsigned)f2bf(v0.z) | ((unsigned)f2bf(v0.w) << 16);
    w.z = (unsigned)f2bf(v1.x) | ((unsigned)f2bf(v1.y) << 16);
    w.w = (unsigned)f2bf(v1.z) | ((unsigned)f2bf(v1.w) << 16);
    s4[ci] = w;
  }
}

// Single fused kernel, all 8 quantizers. R12 structure with a reshaped wave
// tile: 16 rows x 64 codes per wave (wr = wv>>1 in 0..3, wc = wv&1) instead
// of 32x32. This halves areg to [s][kk] = 8 frags = 32 VGPR, dropping total
// register demand to ~105 <= the 128-reg/4-wave budget: the persistent
// scratch spills (R7/R9/R12: VGPR pinned at 64, WRITE ~100 MB) should
// disappear while KEEPING 4 waves/SIMD. Per-acc (kk,s) MFMA order unchanged
// -> bit-identical accs (B re-index: code wc*64+j*16+l15 ==
// (wc*2+(j>>1))*32+(j&1)*16+l15, R6-verified identity). Epilogue: exact min
// over 4 d's then DPP-16 (order-independent), same racy-superset threshold,
// same one-lane atomics, same recheck/tie-break/update chains.
__global__ __launch_bounds__(512)
__attribute__((amdgpu_waves_per_eu(4, 4)))
void rvq_fused_all(const float* __restrict__ z,
                   const float* __restrict__ cb,
                   float* __restrict__ ws,
                   float* __restrict__ out) {
  extern __shared__ __align__(16) char smem[];
  float* RES = (float*)(smem + SM_RES);                // [64][260]
  unsigned int* lcand = (unsigned int*)(smem + SM_LCAND);
  unsigned long long* chc = (unsigned long long*)(smem + SM_CHC);
  float* an_s = (float*)(smem + SM_ANS);
  unsigned int* rowmin = (unsigned int*)(smem + SM_RMIN);
  unsigned int* lcnt = (unsigned int*)(smem + SM_LCNT);
  float* lsum = (float*)(smem + SM_LCNT + 4);

  const int tid = threadIdx.x;
  const int row0 = blockIdx.x * 64;
  const int wv = tid >> 6, lane = tid & 63, quad = lane >> 4, l15 = lane & 15;
  const int wr = wv >> 1, wc = wv & 1;       // 4 row-quarters x 2 code-halves

  // ---- init: copy z tile -> LDS RES (f32 exact), then ANORM(z) np-exact ----
  const float4* zb = (const float4*)(z + (size_t)row0 * DN);
#pragma unroll
  for (int k = 0; k < 8; ++k) {
    int fi = k * 512 + tid;                  // float4 index in 64x256 tile
    int rr = fi >> 6, dd = (fi & 63) * 4;
    *(float4*)&RES[rr * RESW + dd] = zb[fi];
  }
  if (tid == 0) *lsum = 0.f;
  __syncthreads();
  if (tid < 64) an_s[tid] = sum256_sq_np(&RES[tid * RESW]);

  const uint4* Bf = (const uint4*)((const unsigned short*)(ws + WS_CSPLIT));

#pragma unroll 1
  for (int q = 0; q < QN; ++q) {
    const bool last = (q == QN - 1);

    __syncthreads();                         // RES/an_s stable; prior-q consumers done
    if (tid < 64) {
      rowmin[tid] = 0x7f7fffffu;
      chc[tid] = ~0ull;
    }
    if (tid == 0) *lcnt = 0u;

    // a-fragments: 16 rows/wave, cvt RNE -> bf16 regs (8 frags = 32 VGPR)
    short8v areg[2][4];                      // [s][kk]
#pragma unroll
    for (int kk = 0; kk < 4; ++kk) {
#pragma unroll
      for (int s = 0; s < 2; ++s) {
        int ra = wr * 16 + l15;
        int g = kk * 8 + s * 4 + quad;       // 8-dim group: dims g*8..g*8+8
        const float* fp = &RES[ra * RESW + g * 8];
        float4 v0 = *(const float4*)fp;
        float4 v1 = *(const float4*)(fp + 4);
        uint4 w;
        w.x = cvt_pk_bf16(v0.x, v0.y);
        w.y = cvt_pk_bf16(v0.z, v0.w);
        w.z = cvt_pk_bf16(v1.x, v1.y);
        w.w = cvt_pk_bf16(v1.z, v1.w);
        areg[s][kk] = *(short8v*)&w;
      }
    }
    __syncthreads();                         // resets visible; screen may start

    // ---- screen: 8 chunks of 128 codes, barrier-free ----
    const uint4* Bl = Bf + ((size_t)q * 32768 + lane);
    const float* cnq_g = ws + WS_CNORM + q * KN;
    for (int c = 0; c < 8; ++c) {
      float cnr[4];                          // L1-hot scalar norms
#pragma unroll
      for (int j = 0; j < 4; ++j) cnr[j] = cnq_g[c * 128 + wc * 64 + j * 16 + l15];

      f32x4 acc[4];
#pragma unroll
      for (int j = 0; j < 4; ++j) acc[j] = (f32x4){0.f, 0.f, 0.f, 0.f};

      const uint4* Bc = Bl + c * 4096;
#pragma unroll
      for (int kk = 0; kk < 4; ++kk) {
#pragma unroll
        for (int s = 0; s < 2; ++s) {        // braw scoped per-s: 16 live VGPR
          uint4 braw[4];
#pragma unroll
          for (int j = 0; j < 4; ++j)
            braw[j] = Bc[(wc * 2 + (j >> 1)) * 1024 + kk * 256 + s * 128 + (j & 1) * 64];
#pragma unroll
          for (int j = 0; j < 4; ++j)
            acc[j] = __builtin_amdgcn_mfma_f32_16x16x32_bf16(
                areg[s][kk], *(const short8v*)&braw[j], acc[j], 0, 0, 0);
        }
      }

      // merged epilogue: per-row wave-min (DPP, no LDS), racy-safe threshold,
      // append. thr = min(rowmin_read, own chunk wave-min) + MARGIN >= final
      // thr -> candidate superset; exact recheck resolves identically.
#pragma unroll
      for (int reg = 0; reg < 4; ++reg) {
        int rl = wr * 16 + quad * 4 + reg;
        float an = an_s[rl];
        float d0 = __fadd_rn(__fadd_rn(an, -2.0f * acc[0][reg]), cnr[0]);
        float d1 = __fadd_rn(__fadd_rn(an, -2.0f * acc[1][reg]), cnr[1]);
        float d2 = __fadd_rn(__fadd_rn(an, -2.0f * acc[2][reg]), cnr[2]);
        float d3 = __fadd_rn(__fadd_rn(an, -2.0f * acc[3][reg]), cnr[3]);
        float bd = (d0 < d1) ? d0 : d1;
        bd = (d2 < bd) ? d2 : bd;
        bd = (d3 < bd) ? d3 : bd;
        bd = min16_dpp(bd);                  // min over 16 l15 lanes, pure VALU
        float rmf = __uint_as_float(rowmin[rl]);       // racy read: only tightens
        if (l15 == 0) atomicMin(&rowmin[rl], __float_as_uint(bd));
        float tb = (bd < rmf) ? bd : rmf;
        float thr = tb + MARGIN;
        if (d0 <= thr) {
          unsigned int p = atomicAdd(lcnt, 1u);
          if (p < LCAP)
            lcand[p] = ((unsigned)rl << 10) | (unsigned)(c * 128 + wc * 64 + l15);
        }
        if (d1 <= thr) {
          unsigned int p = atomicAdd(lcnt, 1u);
          if (p < LCAP)
            lcand[p] = ((unsigned)rl << 10) | (unsigned)(c * 128 + wc * 64 + 16 + l15);
        }
        if (d2 <= thr) {
          unsigned int p = atomicAdd(lcnt, 1u);
          if (p < LCAP)
            lcand[p] = ((unsigned)rl << 10) | (unsigned)(c * 128 + wc * 64 + 32 + l15);
        }
        if (d3 <= thr) {
          unsigned int p = atomicAdd(lcnt, 1u);
          if (p < LCAP)
            lcand[p] = ((unsigned)rl << 10) | (unsigned)(c * 128 + wc * 64 + 48 + l15);
        }
      }
    }
    __syncthreads();                         // appends + final rowmin + lcnt visible

    // ---- exact recheck: residual rows from LDS (float4), codebook f32 global ----
    const float* cbq = cb + (size_t)q * KN * DN;
    const float* cnq = ws + WS_CNORM + q * KN;
    unsigned int n = *lcnt;
    if (n <= LCAP) {
      for (unsigned int e = tid; e < n; e += 512u) {
        unsigned int en = lcand[e];
        int rl = en >> 10, code = en & 1023;
        const float4* rv4 = (const float4*)&RES[rl * RESW];
        const float4* cv4 = (const float4*)(cbq + (size_t)code * DN);
        float B = 0.f;
#pragma unroll 8
        for (int d4 = 0; d4 < 64; ++d4) {    // same serial chain, vector loads
          float4 rv = rv4[d4], cv = cv4[d4];
          B = fmaf(rv.x, cv.x, B); B = fmaf(rv.y, cv.y, B);
          B = fmaf(rv.z, cv.z, B); B = fmaf(rv.w, cv.w, B);
        }
        float de = __fadd_rn(__fadd_rn(an_s[rl], -2.0f * B), cnq[code]);
        unsigned long long key = ((unsigned long long)__float_as_uint(de) << 32) | (unsigned)code;
        atomicMin(&chc[rl], key);
      }
    } else {
      // safety fallback: exhaustive exact argmin (correct; expected never)
      for (int e = tid; e < 64 * 1024; e += 512) {
        int rl = e >> 10, code = e & 1023;
        const float4* rv4 = (const float4*)&RES[rl * RESW];
        const float4* cv4 = (const float4*)(cbq + (size_t)code * DN);
        float B = 0.f;
#pragma unroll 8
        for (int d4 = 0; d4 < 64; ++d4) {
          float4 rv = rv4[d4], cv = cv4[d4];
          B = fmaf(rv.x, cv.x, B); B = fmaf(rv.y, cv.y, B);
          B = fmaf(rv.z, cv.z, B); B = fmaf(rv.w, cv.w, B);
        }
        float de = __fadd_rn(__fadd_rn(an_s[rl], -2.0f * B), cnq[code]);
        unsigned long long key = ((unsigned long long)__float_as_uint(de) << 32) | (unsigned)code;
        atomicMin(&chc[rl], key);
      }
    }
    __syncthreads();                        // chc final

    // ---- np-exact update in LDS: 2 passes x 32 rows, 16 thr/row x 16 dims ----
    const int ur = tid >> 4, ud = tid & 15;  // ur in 0..31
    float lp = 0.f;
    for (int pass = 0; pass < 2; ++pass) {
      int rl = pass * 32 + ur;
      int row = row0 + rl;
      int idx = (int)(chc[rl] & 1023u);
      if (ud == 0) out[IDX_BASE + (size_t)q * NROWS + row] = (float)idx;

      float4* r4 = (float4*)&RES[rl * RESW + ud * 16];
      const float4* q4 = (const float4*)(cb + ((size_t)q * KN + idx) * DN) + ud * 4;
      float4 rnb[4];
#pragma unroll
      for (int t = 0; t < 4; ++t) {
        float4 r = r4[t], qv = q4[t];
        float tx = __fadd_rn(qv.x, -r.x), ty = __fadd_rn(qv.y, -r.y);
        float tz = __fadd_rn(qv.z, -r.z), tw = __fadd_rn(qv.w, -r.w);
        float sx = __fadd_rn(r.x, tx), sy = __fadd_rn(r.y, ty);
        float sz = __fadd_rn(r.z, tz), sw = __fadd_rn(r.w, tw);
        rnb[t] = make_float4(__fadd_rn(r.x, -sx), __fadd_rn(r.y, -sy),
                             __fadd_rn(r.z, -sz), __fadd_rn(r.w, -sw));
        lp = fmaf(tx, tx, lp); lp = fmaf(ty, ty, lp);
        lp = fmaf(tz, tz, lp); lp = fmaf(tw, tw, lp);
      }

      if (last) {
        const float4* z4 = (const float4*)(z + (size_t)row * DN) + ud * 4;
        float4* o4 = (float4*)(out + (size_t)row * DN) + ud * 4;
#pragma unroll
        for (int t = 0; t < 4; ++t) {
          float4 zv = z4[t];
          o4[t] = make_float4(__fadd_rn(zv.x, -rnb[t].x), __fadd_rn(zv.y, -rnb[t].y),
                              __fadd_rn(zv.z, -rnb[t].z), __fadd_rn(zv.w, -rnb[t].w));
        }
      } else {
#pragma unroll
        for (int t = 0; t < 4; ++t) r4[t] = rnb[t];   // residual stays in LDS
      }
    }

#pragma unroll
    for (int off = 32; off > 0; off >>= 1) lp += __shfl_down(lp, off, 64);
    if (lane == 0) atomicAdd(lsum, lp);     // LDS f32 add: 8 wave partials

    __syncthreads();                        // RES updates + lsum complete
    if (!last && tid < 64) an_s[tid] = sum256_sq_np(&RES[tid * RESW]);
    if (tid == 0) {                         // one global atomic per block per q
      atomicAdd(ws + WS_LOSS + q, *lsum);
      *lsum = 0.f;
    }
  }
}

__global__ void rvq_fin(const float* __restrict__ ws, float* __restrict__ out) {
  if (blockIdx.x == 0 && threadIdx.x == 0) {
    float vq = 0.f;
    for (int q = 0; q < QN; ++q) {
      float m = ws[WS_LOSS + q] / 8388608.0f;
      float l = __fadd_rn(m, 0.25f * m);
      vq = __fadd_rn(vq, l);
    }
    out[LOSS_OFF] = vq;
  }
}

extern "C" void kernel_launch(void* const* d_in, const int* in_sizes, int n_in,
                              void* d_out, int out_size, void* d_ws, size_t ws_size,
                              hipStream_t stream) {
  const float* z = (const float*)d_in[0];
  const float* cb = (const float*)d_in[1];
  float* out = (float*)d_out;
  float* ws = (float*)d_ws;

  hipLaunchKernelGGL(rvq_prep_norm, dim3(32), dim3(256), 0, stream, cb, ws);
  hipLaunchKernelGGL(rvq_prep_cast, dim3(512), dim3(256), 0, stream, cb,
                     (unsigned short*)(ws + WS_CSPLIT));
  hipLaunchKernelGGL(rvq_fused_all, dim3(512), dim3(512), SM_BYTES, stream, z, cb, ws, out);
  hipLaunchKernelGGL(rvq_fin, dim3(1), dim3(64), 0, stream, ws, out);
}